// Round 2
// baseline (662.439 us; speedup 1.0000x reference)
//
#include <hip/hip_runtime.h>
#include <hip/hip_bf16.h>

#define T_SEQ 1024
#define NH 8
#define DH 512
#define HK 4096

typedef __attribute__((ext_vector_type(8))) __bf16 bf16x8;
typedef __attribute__((ext_vector_type(4))) float f32x4;

#define QK_SCALE 0.21022410381342863f  // 512^-0.25

static __device__ __forceinline__ unsigned short f2bu(float f) {
  union { __hip_bfloat16 h; unsigned short u; } cv;
  cv.h = __float2bfloat16(f);
  return cv.u;
}

#define GLOAD_LDS16(gsrc, ldst) \
  __builtin_amdgcn_global_load_lds((const __attribute__((address_space(1))) void*)(gsrc), \
                                   (__attribute__((address_space(3))) void*)(ldst), 16, 0, 0)

// ---------------- convert / transpose ----------------
__global__ void cvt_bf16_kernel(const float* __restrict__ in, unsigned short* __restrict__ out, int n4) {
  int i = blockIdx.x * blockDim.x + threadIdx.x;
  if (i >= n4) return;
  const float4 v = reinterpret_cast<const float4*>(in)[i];
  ushort4 u; u.x = f2bu(v.x); u.y = f2bu(v.y); u.z = f2bu(v.z); u.w = f2bu(v.w);
  reinterpret_cast<ushort4*>(out)[i] = u;
}

// out[C][R] = bf16(in[R][C])
__global__ void transpose_cvt_kernel(const float* __restrict__ in, unsigned short* __restrict__ out,
                                     int R, int C) {
  __shared__ float tile[32][33];
  const int c0 = blockIdx.x * 32, r0 = blockIdx.y * 32;
  const int tx = threadIdx.x, ty = threadIdx.y;
  #pragma unroll
  for (int i = ty; i < 32; i += 8)
    tile[i][tx] = in[(size_t)(r0 + i) * C + (c0 + tx)];
  __syncthreads();
  #pragma unroll
  for (int i = ty; i < 32; i += 8)
    out[(size_t)(c0 + i) * R + (r0 + tx)] = f2bu(tile[tx][i]);
}

// ---------------- projection GEMM: C = A[M,512] @ Bt[N,512]^T ----------------
// MODE 0/1: Q/K (scaled, (b,t,h,d) row-major). MODE 2: V -> transposed (b,h,d,t).
// A is chunk-local (M = NB*1024 rows); C chunk-local.
template<int MODE>
__global__ __launch_bounds__(256, 2)
void gemm_proj(const unsigned short* __restrict__ A,
               const unsigned short* __restrict__ Bt,
               unsigned short* __restrict__ C) {
  __shared__ __align__(16) char As[128 * 128];  // 128 rows x 64 bf16 (BK=64)
  __shared__ __align__(16) char Bs[128 * 128];
  const int tid = threadIdx.x, lane = tid & 63, w = tid >> 6;
  const int wr = w >> 1, wc = w & 1;
  const int n0 = blockIdx.x * 128, m0 = blockIdx.y * 128;
  const int Kd = 512;

  f32x4 acc[4][4];
  #pragma unroll
  for (int i = 0; i < 4; ++i)
    #pragma unroll
    for (int j = 0; j < 4; ++j)
      acc[i][j] = f32x4{0.f, 0.f, 0.f, 0.f};

  for (int kt = 0; kt < Kd; kt += 64) {
    __syncthreads();
    #pragma unroll
    for (int is = 0; is < 4; ++is) {
      const int ob = is * 4096 + w * 1024;       // wave-uniform LDS byte base
      const int ol = ob + lane * 16;
      const int row = ol >> 7;
      const int bo = ol & 127;
      const int sw = (row & 7) << 4;             // XOR swizzle, both sides
      GLOAD_LDS16((const char*)A + ((size_t)(m0 + row) * Kd + kt) * 2 + (bo ^ sw), As + ob);
      GLOAD_LDS16((const char*)Bt + ((size_t)(n0 + row) * Kd + kt) * 2 + (bo ^ sw), Bs + ob);
    }
    __syncthreads();
    #pragma unroll
    for (int ks = 0; ks < 2; ++ks) {
      bf16x8 af[4], bfr[4];
      #pragma unroll
      for (int mi = 0; mi < 4; ++mi) {
        const int row = wr * 64 + mi * 16 + (lane & 15);
        af[mi] = *reinterpret_cast<const bf16x8*>(
            As + row * 128 + ((ks * 64 + ((lane >> 4) << 4)) ^ ((row & 7) << 4)));
      }
      #pragma unroll
      for (int ni = 0; ni < 4; ++ni) {
        const int row = wc * 64 + ni * 16 + (lane & 15);
        bfr[ni] = *reinterpret_cast<const bf16x8*>(
            Bs + row * 128 + ((ks * 64 + ((lane >> 4) << 4)) ^ ((row & 7) << 4)));
      }
      #pragma unroll
      for (int mi = 0; mi < 4; ++mi)
        #pragma unroll
        for (int ni = 0; ni < 4; ++ni)
          acc[mi][ni] = __builtin_amdgcn_mfma_f32_16x16x32_bf16(af[mi], bfr[ni], acc[mi][ni], 0, 0, 0);
    }
  }

  #pragma unroll
  for (int mi = 0; mi < 4; ++mi) {
    #pragma unroll
    for (int ni = 0; ni < 4; ++ni) {
      const int mb = m0 + wr * 64 + mi * 16 + ((lane >> 4) << 2);  // 4 consecutive rows
      const int n = n0 + wc * 64 + ni * 16 + (lane & 15);
      if (MODE < 2) {
        #pragma unroll
        for (int r = 0; r < 4; ++r)
          C[(size_t)(mb + r) * HK + n] = f2bu(acc[mi][ni][r] * QK_SCALE);
      } else {
        const int b = mb >> 10, t = mb & 1023, hh = n >> 9, d = n & 511;
        ushort4 u;
        u.x = f2bu(acc[mi][ni][0]); u.y = f2bu(acc[mi][ni][1]);
        u.z = f2bu(acc[mi][ni][2]); u.w = f2bu(acc[mi][ni][3]);
        *reinterpret_cast<ushort4*>(&C[((size_t)(b * NH + hh) * DH + d) * T_SEQ + t]) = u;
      }
    }
  }
}

// ---------------- output GEMM: out = Ob[M,4096] @ Wut[512,4096]^T + bu ----------------
__global__ __launch_bounds__(256, 2)
void gemm_out(const unsigned short* __restrict__ A,
              const unsigned short* __restrict__ Bt,
              const float* __restrict__ bias,
              float* __restrict__ C) {
  __shared__ __align__(16) char As[128 * 128];
  __shared__ __align__(16) char Bs[128 * 128];
  const int tid = threadIdx.x, lane = tid & 63, w = tid >> 6;
  const int wr = w >> 1, wc = w & 1;
  const int n0 = blockIdx.x * 128, m0 = blockIdx.y * 128;
  const int Kd = HK;

  f32x4 acc[4][4];
  #pragma unroll
  for (int i = 0; i < 4; ++i)
    #pragma unroll
    for (int j = 0; j < 4; ++j)
      acc[i][j] = f32x4{0.f, 0.f, 0.f, 0.f};

  for (int kt = 0; kt < Kd; kt += 64) {
    __syncthreads();
    #pragma unroll
    for (int is = 0; is < 4; ++is) {
      const int ob = is * 4096 + w * 1024;
      const int ol = ob + lane * 16;
      const int row = ol >> 7;
      const int bo = ol & 127;
      const int sw = (row & 7) << 4;
      GLOAD_LDS16((const char*)A + ((size_t)(m0 + row) * Kd + kt) * 2 + (bo ^ sw), As + ob);
      GLOAD_LDS16((const char*)Bt + ((size_t)(n0 + row) * Kd + kt) * 2 + (bo ^ sw), Bs + ob);
    }
    __syncthreads();
    #pragma unroll
    for (int ks = 0; ks < 2; ++ks) {
      bf16x8 af[4], bfr[4];
      #pragma unroll
      for (int mi = 0; mi < 4; ++mi) {
        const int row = wr * 64 + mi * 16 + (lane & 15);
        af[mi] = *reinterpret_cast<const bf16x8*>(
            As + row * 128 + ((ks * 64 + ((lane >> 4) << 4)) ^ ((row & 7) << 4)));
      }
      #pragma unroll
      for (int ni = 0; ni < 4; ++ni) {
        const int row = wc * 64 + ni * 16 + (lane & 15);
        bfr[ni] = *reinterpret_cast<const bf16x8*>(
            Bs + row * 128 + ((ks * 64 + ((lane >> 4) << 4)) ^ ((row & 7) << 4)));
      }
      #pragma unroll
      for (int mi = 0; mi < 4; ++mi)
        #pragma unroll
        for (int ni = 0; ni < 4; ++ni)
          acc[mi][ni] = __builtin_amdgcn_mfma_f32_16x16x32_bf16(af[mi], bfr[ni], acc[mi][ni], 0, 0, 0);
    }
  }

  #pragma unroll
  for (int mi = 0; mi < 4; ++mi) {
    #pragma unroll
    for (int ni = 0; ni < 4; ++ni) {
      const int mb = m0 + wr * 64 + mi * 16 + ((lane >> 4) << 2);
      const int n = n0 + wc * 64 + ni * 16 + (lane & 15);
      const float bn = bias[n];
      #pragma unroll
      for (int r = 0; r < 4; ++r)
        C[(size_t)(mb + r) * DH + n] = acc[mi][ni][r] + bn;
    }
  }
}

// ---------------- flash attention ----------------
// grid (T/32, H, NB), 256 threads (4 waves). Q in regs; K,Vt in swizzled LDS.
__global__ __launch_bounds__(256, 2)
void attn_kernel(const unsigned short* __restrict__ Qg,
                 const unsigned short* __restrict__ Kg,
                 const unsigned short* __restrict__ Vtg,
                 unsigned short* __restrict__ Og) {
  __shared__ __align__(16) char Ks[32 * 1024];     // 32 x 512 bf16, row-swz (row&7)<<4
  __shared__ __align__(16) char Vts[512 * 64];     // 512 x 32 bf16, row-swz (row&3)<<4
  __shared__ float S_lds[32 * 33];
  __shared__ __align__(16) char P_lds[32 * 64];    // 32 x 32 bf16, swz (r&3)<<4
  __shared__ __align__(16) float Mrow[32], Lrow[32], Arow[32];

  const int tid = threadIdx.x, lane = tid & 63, w = tid >> 6;
  const int qt = blockIdx.x, h = blockIdx.y, b = blockIdx.z;
  const int bh = b * NH + h;

  bf16x8 qreg[16];
  {
    const int qrow = qt * 32 + (w >> 1) * 16 + (lane & 15);
    const unsigned short* qp = Qg + ((size_t)(b * T_SEQ + qrow) * NH + h) * DH + ((lane >> 4) << 3);
    #pragma unroll
    for (int k2 = 0; k2 < 16; ++k2)
      qreg[k2] = *reinterpret_cast<const bf16x8*>(qp + k2 * 32);
  }

  f32x4 o[2][8];
  #pragma unroll
  for (int mi = 0; mi < 2; ++mi)
    #pragma unroll
    for (int ni = 0; ni < 8; ++ni)
      o[mi][ni] = f32x4{0.f, 0.f, 0.f, 0.f};

  if (tid < 32) { Mrow[tid] = -INFINITY; Lrow[tid] = 0.f; }

  const char* Kbase = (const char*)(Kg + ((size_t)b * T_SEQ * NH + h) * DH);  // t stride 8192 B
  const char* Vbase = (const char*)(Vtg + (size_t)bh * DH * T_SEQ);           // d stride 2048 B

  for (int st = 0; st <= qt; ++st) {
    __syncthreads();
    #pragma unroll
    for (int is = 0; is < 8; ++is) {
      const int ob = is * 4096 + w * 1024;
      const int ol = ob + lane * 16;
      { const int row = ol >> 10, bo = ol & 1023;
        GLOAD_LDS16(Kbase + (size_t)(st * 32 + row) * 8192 + (bo ^ ((row & 7) << 4)), Ks + ob); }
      { const int row = ol >> 6, bo = ol & 63;
        GLOAD_LDS16(Vbase + (size_t)row * 2048 + st * 64 + (bo ^ ((row & 3) << 4)), Vts + ob); }
    }
    __syncthreads();

    // S = Q K^T : one 16x16 fragment per wave
    const int i_half = w >> 1, j_half = w & 1;
    f32x4 s = f32x4{0.f, 0.f, 0.f, 0.f};
    {
      const int krow = j_half * 16 + (lane & 15);
      const char* kr = Ks + krow * 1024;
      const int sw = (krow & 7) << 4;
      #pragma unroll
      for (int ks = 0; ks < 16; ++ks) {
        bf16x8 kf = *reinterpret_cast<const bf16x8*>(kr + ((ks * 64 + ((lane >> 4) << 4)) ^ sw));
        s = __builtin_amdgcn_mfma_f32_16x16x32_bf16(qreg[ks], kf, s, 0, 0, 0);
      }
    }
    {
      const int col = j_half * 16 + (lane & 15);
      const int rbase = i_half * 16 + ((lane >> 4) << 2);
      #pragma unroll
      for (int r = 0; r < 4; ++r) S_lds[(rbase + r) * 33 + col] = s[r];
    }
    __syncthreads();

    // online softmax: 8 threads per row
    {
      const int r = tid >> 3, cg = tid & 7;
      const int grow = qt * 32 + r;
      float sv[4];
      #pragma unroll
      for (int j = 0; j < 4; ++j) {
        const int c = cg * 4 + j;
        const float x = S_lds[r * 33 + c];
        sv[j] = (st * 32 + c > grow) ? -INFINITY : x;
      }
      float pm = fmaxf(fmaxf(sv[0], sv[1]), fmaxf(sv[2], sv[3]));
      pm = fmaxf(pm, __shfl_xor(pm, 1));
      pm = fmaxf(pm, __shfl_xor(pm, 2));
      pm = fmaxf(pm, __shfl_xor(pm, 4));
      const float m_old = Mrow[r];
      const float m_new = fmaxf(m_old, pm);
      float ps = 0.f;
      ushort4 pu;
      { float p0 = __expf(sv[0] - m_new), p1 = __expf(sv[1] - m_new),
              p2 = __expf(sv[2] - m_new), p3 = __expf(sv[3] - m_new);
        ps = p0 + p1 + p2 + p3;
        pu.x = f2bu(p0); pu.y = f2bu(p1); pu.z = f2bu(p2); pu.w = f2bu(p3); }
      *reinterpret_cast<ushort4*>(P_lds + r * 64 + ((cg * 8) ^ ((r & 3) << 4))) = pu;
      ps += __shfl_xor(ps, 1);
      ps += __shfl_xor(ps, 2);
      ps += __shfl_xor(ps, 4);
      if (cg == 0) {
        const float alpha = __expf(m_old - m_new);
        Arow[r] = alpha;
        Mrow[r] = m_new;
        Lrow[r] = alpha * Lrow[r] + ps;
      }
    }
    __syncthreads();

    // rescale O and accumulate PV (wave w: cols w*128..+128)
    {
      bf16x8 pf[2];
      #pragma unroll
      for (int mi = 0; mi < 2; ++mi) {
        const int pr = mi * 16 + (lane & 15);
        pf[mi] = *reinterpret_cast<const bf16x8*>(
            P_lds + pr * 64 + ((((lane >> 4) << 4)) ^ ((pr & 3) << 4)));
      }
      #pragma unroll
      for (int mi = 0; mi < 2; ++mi) {
        const int rb = mi * 16 + ((lane >> 4) << 2);
        const f32x4 al = f32x4{Arow[rb], Arow[rb + 1], Arow[rb + 2], Arow[rb + 3]};
        #pragma unroll
        for (int ni = 0; ni < 8; ++ni) o[mi][ni] *= al;
      }
      #pragma unroll
      for (int ni = 0; ni < 8; ++ni) {
        const int vr = w * 128 + ni * 16 + (lane & 15);
        bf16x8 vf = *reinterpret_cast<const bf16x8*>(
            Vts + vr * 64 + ((((lane >> 4) << 4)) ^ ((vr & 3) << 4)));
        o[0][ni] = __builtin_amdgcn_mfma_f32_16x16x32_bf16(pf[0], vf, o[0][ni], 0, 0, 0);
        o[1][ni] = __builtin_amdgcn_mfma_f32_16x16x32_bf16(pf[1], vf, o[1][ni], 0, 0, 0);
      }
    }
  }

  #pragma unroll
  for (int mi = 0; mi < 2; ++mi) {
    const int rb = mi * 16 + ((lane >> 4) << 2);
    f32x4 li;
    #pragma unroll
    for (int r = 0; r < 4; ++r) li[r] = 1.f / Lrow[rb + r];
    #pragma unroll
    for (int ni = 0; ni < 8; ++ni) {
      const int d = w * 128 + ni * 16 + (lane & 15);
      const size_t base = ((size_t)(b * T_SEQ + qt * 32 + rb) * NH + h) * DH + d;
      #pragma unroll
      for (int r = 0; r < 4; ++r)
        Og[base + (size_t)r * NH * DH] = f2bu(o[mi][ni][r] * li[r]);
    }
  }
}

// ---------------- host launch (adaptive workspace chunking) ----------------
extern "C" void kernel_launch(void* const* d_in, const int* in_sizes, int n_in,
                              void* d_out, int out_size, void* d_ws, size_t ws_size,
                              hipStream_t stream) {
  (void)in_sizes; (void)n_in; (void)out_size;
  const float* x  = (const float*)d_in[0];
  const float* Wq = (const float*)d_in[1];
  const float* Wk = (const float*)d_in[2];
  const float* Wv = (const float*)d_in[3];
  const float* Wu = (const float*)d_in[4];
  const float* bu = (const float*)d_in[5];
  float* out = (float*)d_out;

  // persistent: xb 8MB + Wq/Wk/Wv^T 12MB + Wu^T 4MB = 24MB
  const size_t PERS = (size_t)8192 * 512 * 2 + 3 * (size_t)4096 * 512 * 2 + (size_t)512 * 4096 * 2;
  // per-chunk: Q,K,Vt,O each NB*1024*4096*2 bytes
  int NB = 8;
  while (NB > 1 && PERS + 4 * ((size_t)NB * 1024 * 4096 * 2) + 8192 > ws_size) NB >>= 1;

  size_t off = 0;
  auto wsp = [&](size_t bytes) {
    char* p = (char*)d_ws + off;
    off += (bytes + 255) & ~(size_t)255;
    return p;
  };
  unsigned short* xb  = (unsigned short*)wsp((size_t)8192 * 512 * 2);
  unsigned short* Wqt = (unsigned short*)wsp((size_t)4096 * 512 * 2);
  unsigned short* Wkt = (unsigned short*)wsp((size_t)4096 * 512 * 2);
  unsigned short* Wvt = (unsigned short*)wsp((size_t)4096 * 512 * 2);
  unsigned short* Wut = (unsigned short*)wsp((size_t)512 * 4096 * 2);
  const size_t CHB = (size_t)NB * 1024 * 4096 * 2;
  unsigned short* Qc = (unsigned short*)wsp(CHB);
  unsigned short* Kc = (unsigned short*)wsp(CHB);
  unsigned short* Vc = (unsigned short*)wsp(CHB);
  unsigned short* Oc = (unsigned short*)wsp(CHB);

  cvt_bf16_kernel<<<4096, 256, 0, stream>>>(x, xb, 8192 * 512 / 4);
  transpose_cvt_kernel<<<dim3(128, 16), dim3(32, 8), 0, stream>>>(Wq, Wqt, 512, 4096);
  transpose_cvt_kernel<<<dim3(128, 16), dim3(32, 8), 0, stream>>>(Wk, Wkt, 512, 4096);
  transpose_cvt_kernel<<<dim3(128, 16), dim3(32, 8), 0, stream>>>(Wv, Wvt, 512, 4096);
  transpose_cvt_kernel<<<dim3(16, 128), dim3(32, 8), 0, stream>>>(Wu, Wut, 4096, 512);

  const int nchunks = 8 / NB;
  for (int c = 0; c < nchunks; ++c) {
    const unsigned short* xc = xb + (size_t)c * NB * 1024 * 512;
    gemm_proj<0><<<dim3(32, NB * 8), 256, 0, stream>>>(xc, Wqt, Qc);
    gemm_proj<1><<<dim3(32, NB * 8), 256, 0, stream>>>(xc, Wkt, Kc);
    gemm_proj<2><<<dim3(32, NB * 8), 256, 0, stream>>>(xc, Wvt, Vc);
    attn_kernel<<<dim3(32, 8, NB), 256, 0, stream>>>(Qc, Kc, Vc, Oc);
    gemm_out<<<dim3(4, NB * 8), 256, 0, stream>>>(Oc, Wut, bu, out + (size_t)c * NB * 1024 * 512);
  }
}